// Round 23
// baseline (851.509 us; speedup 1.0000x reference)
//
#include <hip/hip_runtime.h>
#include <cstddef>
#include <cstdint>

#define TOK    49      // tokens (7x7)
#define KD     32      // key dim
#define NH     8       // heads
#define DHEAD  128     // v head dim
#define HQKV   1536    // qkv channels
#define DHTOT  1024    // NH*DHEAD
#define DIMM   384     // model dim

typedef unsigned short u16;
typedef float  f32x4  __attribute__((ext_vector_type(4)));
typedef __bf16 bf16x8 __attribute__((ext_vector_type(8)));

typedef const __attribute__((address_space(1))) void gas_void;
typedef __attribute__((address_space(3))) void las_void;

static __device__ __forceinline__ u16 f2bf(float f) {
    unsigned int u = __builtin_bit_cast(unsigned int, f);
    return (u16)((u + 0x7fffu + ((u >> 16) & 1u)) >> 16);   // RNE
}

// XOR-swizzled index into a row-major [*][64] bf16 LDS image (QKs/Ps).
static __device__ __forceinline__ int swz(int row, int c) {
    return (row << 6) + ((((c >> 3) ^ (row & 7)) << 3) | (c & 7));
}

// Vts swizzle (validated r13): XOR both row&7 and (row>>3)&7.
static __device__ __forceinline__ int swzV(int row, int c) {
    return (row << 6) + ((((c >> 3) ^ (row & 7) ^ ((row >> 3) & 7)) << 3) | (c & 7));
}

// Frag offset in a [rows][384] bf16 LDS image whose content is pre-swizzled
// per 64-elem K-panel (slot ^= row&7). e = element col (multiple of 8).
static __device__ __forceinline__ int frag384(int row, int e) {
    return row * 384 + (e & ~63) + ((((e >> 3) & 7) ^ (row & 7)) << 3);
}

// Fragment read offset in a [rows][64]-short LDS tile with pre-swz content.
static __device__ __forceinline__ int frag_off(int row, int ks8fg) {
    return (row << 6) + (((ks8fg ^ (row & 7)) << 3));
}

// Bijective XCD-chunked remap (m204).
static __device__ __forceinline__ int xcd_chunk(int bid, int nwg) {
    const int xcd = bid & 7, slot = bid >> 3;
    const int q = nwg >> 3, r = nwg & 7;
    return (xcd < r ? xcd * (q + 1) : r * (q + 1) + (xcd - r) * q) + slot;
}

#define BAR() __builtin_amdgcn_s_barrier()
#define WAIT_VM6()  asm volatile("s_waitcnt vmcnt(6)"  ::: "memory")
#define WAIT_VM0()  asm volatile("s_waitcnt vmcnt(0)"  ::: "memory")
// Barrier that does NOT drain vmcnt (r14/r17-validated).
#define LGKM0_BAR() do { asm volatile("s_waitcnt lgkmcnt(0)" ::: "memory"); \
                         __builtin_amdgcn_s_barrier(); } while (0)
// Wave-local LDS fence (rule #18; r22-validated).
#define LGKM0_FENCE() do { asm volatile("s_waitcnt lgkmcnt(0)" ::: "memory"); \
                           __builtin_amdgcn_sched_barrier(0); } while (0)

// ---------------------------------------------------------------------------
// fp32 -> bf16 cast with T2 pre-swizzle (weights; validated r10-r13).
// ---------------------------------------------------------------------------
__global__ __launch_bounds__(256)
void cast_swz(const float* __restrict__ in, u16* __restrict__ out, int K8, long nchunk)
{
    long i = (long)blockIdx.x * 256 + threadIdx.x;
    const long stride = (long)gridDim.x * 256;
    for (; i < nchunk; i += stride) {
        const long row = i / K8;
        const int  c8  = (int)(i - row * K8);
        const int  slot = c8 & 7, tpan = c8 >> 3;
        float4 v0 = reinterpret_cast<const float4*>(in)[i * 2];
        float4 v1 = reinterpret_cast<const float4*>(in)[i * 2 + 1];
        uint4 o;
        o.x = f2bf(v0.x) | ((unsigned)f2bf(v0.y) << 16);
        o.y = f2bf(v0.z) | ((unsigned)f2bf(v0.w) << 16);
        o.z = f2bf(v1.x) | ((unsigned)f2bf(v1.y) << 16);
        o.w = f2bf(v1.z) | ((unsigned)f2bf(v1.w) << 16);
        *reinterpret_cast<uint4*>(out + row * (long)K8 * 8 + tpan * 64 +
                                  ((slot ^ ((int)row & 7)) << 3)) = o;
    }
}

// ---------------------------------------------------------------------------
// bias_full[h][n*49+m] = attn_bias[h][bias_idxs[n*49+m]]
// ---------------------------------------------------------------------------
__global__ __launch_bounds__(256)
void bias_expand(const float* __restrict__ attn_bias, const int* __restrict__ idxs,
                 float* __restrict__ bias_full, int n_off)
{
    int i = blockIdx.x * 256 + threadIdx.x;
    if (i < NH * TOK * TOK) {
        int h = i / (TOK * TOK), s = i - h * (TOK * TOK);
        bias_full[i] = attn_bias[h * n_off + idxs[s]];
    }
}

// ---------------------------------------------------------------------------
// QKV GEMM, W-STATIONARY (barrier-free): block owns 64 output channels;
// W[bn..bn+64][384] staged ONCE into LDS (48 KB, pre-swz); then each wave
// independently streams 32-row A-panels: A-frags straight from fp32 X into
// registers (native bf16 casts), B-frags from read-only LDS, 96 MFMA/panel,
// direct stores. NO barriers in the loop -> waves fully pipeline.
// ---------------------------------------------------------------------------
#define MCH 3584   // rows per block (28 panels of 32 rows -> 7 per wave... 28/4=7? no: 112/4=28 per wave)
__global__ __launch_bounds__(256, 3)
void gemm_qkv(const float* __restrict__ X,    // [M][384] fp32 (original x)
              const u16* __restrict__ W,      // [1536][384] bf16 pre-swz
              const float* __restrict__ bias, // [1536]
              u16* __restrict__ qkvb, int M)
{
    const int nMch = (M + MCH - 1) / MCH;
    const int nwg  = nMch * 24;
    const int wgid = xcd_chunk(blockIdx.x, nwg);
    const int mch  = wgid / 24;                // col-fastest: same-M neighbors share XCD L2
    const int cb   = wgid % 24;
    const int bn   = cb * 64;                  // output-channel base

    __shared__ u16 Wl[64 * 384];               // 49,152 B -> 3 blocks/CU

    const int t    = threadIdx.x;
    const int lane = t & 63;
    const int w    = t >> 6;
    const int fr   = lane & 15;
    const int fg   = lane >> 4;

    // stage W panel (pre-swz global -> linear LDS copy preserves swizzle)
    #pragma unroll
    for (int i = 0; i < 12; ++i) {
        const int off = (i * 256 + t) * 8;
        __builtin_amdgcn_global_load_lds((gas_void*)(W + (size_t)bn * 384 + off),
                                         (las_void*)(Wl + off), 16, 0, 0);
    }
    WAIT_VM0();
    BAR();                                     // the ONLY barrier in this kernel

    float bv[4];
    #pragma unroll
    for (int nc = 0; nc < 4; ++nc) bv[nc] = bias[bn + nc * 16 + fr];

    const int npan = MCH / 128;                // 28 panel-rounds (4 waves x 32 rows each)
    for (int p = 0; p < npan; ++p) {
        const int m0 = mch * MCH + (p * 4 + w) * 32;
        if (m0 >= M) break;                    // uniform per wave; no barriers -> safe

        f32x4 acc[2][4];
        #pragma unroll
        for (int mi = 0; mi < 2; ++mi)
            #pragma unroll
            for (int nc = 0; nc < 4; ++nc) acc[mi][nc] = (f32x4)0.0f;

        #pragma unroll
        for (int half = 0; half < 2; ++half) {
            bf16x8 a[2][6];
            #pragma unroll
            for (int mi = 0; mi < 2; ++mi)
                #pragma unroll
                for (int q = 0; q < 6; ++q) {
                    const int kk = half * 6 + q;
                    const float* ap = X + (size_t)(m0 + mi * 16 + fr) * DIMM + kk * 32 + fg * 8;
                    const float4 L0 = *reinterpret_cast<const float4*>(ap);
                    const float4 L1 = *reinterpret_cast<const float4*>(ap + 4);
                    bf16x8 r;
                    r[0] = (__bf16)L0.x; r[1] = (__bf16)L0.y;
                    r[2] = (__bf16)L0.z; r[3] = (__bf16)L0.w;
                    r[4] = (__bf16)L1.x; r[5] = (__bf16)L1.y;
                    r[6] = (__bf16)L1.z; r[7] = (__bf16)L1.w;
                    a[mi][q] = r;
                }
            #pragma unroll
            for (int q = 0; q < 6; ++q) {
                const int kk = half * 6 + q;
                #pragma unroll
                for (int nc = 0; nc < 4; ++nc) {
                    bf16x8 bfr = *reinterpret_cast<const bf16x8*>(
                        &Wl[frag384(nc * 16 + fr, kk * 32 + fg * 8)]);
                    acc[0][nc] = __builtin_amdgcn_mfma_f32_16x16x32_bf16(a[0][q], bfr, acc[0][nc], 0, 0, 0);
                    acc[1][nc] = __builtin_amdgcn_mfma_f32_16x16x32_bf16(a[1][q], bfr, acc[1][nc], 0, 0, 0);
                }
            }
        }

        #pragma unroll
        for (int mi = 0; mi < 2; ++mi)
            #pragma unroll
            for (int nc = 0; nc < 4; ++nc)
                #pragma unroll
                for (int j = 0; j < 4; ++j)
                    qkvb[(size_t)(m0 + mi * 16 + fg * 4 + j) * HQKV + bn + nc * 16 + fr] =
                        f2bf(acc[mi][nc][j] + bv[nc]);
    }
}

// ---------------------------------------------------------------------------
// Proj GEMM (validated r18/r19): BM=64 x BN=128, T4 vmcnt(6).
// ---------------------------------------------------------------------------
__global__ __launch_bounds__(256)
void gemm_bf16_nt(const u16* __restrict__ A, const u16* __restrict__ W,
                  const float* __restrict__ bias, float* __restrict__ C,
                  int M, int N, int K)
{
    const int NB = N / 128;
    const int nwg = (M / 64) * NB;
    const int wgid = xcd_chunk(blockIdx.x, nwg);
    const int bm = (wgid / NB) * 64;
    const int bn = (wgid % NB) * 128;

    __shared__ u16 Alds[2][64 * 64];
    __shared__ u16 Blds[2][128 * 64];

    const int t    = threadIdx.x;
    const int lane = t & 63;
    const int wv   = t >> 6;
    const int lrow = lane >> 3;
    const int lcol = (lane & 7) * 8;
    const int frow = lane & 15;
    const int fg   = lane >> 4;

    f32x4 acc[4][2];
    #pragma unroll
    for (int mi = 0; mi < 4; ++mi)
        #pragma unroll
        for (int nc = 0; nc < 2; ++nc) acc[mi][nc] = (f32x4)0.0f;

    auto STAGE = [&](int buf, int k0) {
        #pragma unroll
        for (int i = 0; i < 2; ++i) {
            const int c   = i * 4 + wv;
            const int row = c * 8 + lrow;
            __builtin_amdgcn_global_load_lds((gas_void*)(A + (size_t)(bm + row) * K + k0 + lcol),
                                             (las_void*)(&Alds[buf][c * 512]), 16, 0, 0);
        }
        #pragma unroll
        for (int i = 0; i < 4; ++i) {
            const int c   = i * 4 + wv;
            const int row = c * 8 + lrow;
            __builtin_amdgcn_global_load_lds((gas_void*)(W + (size_t)(bn + row) * K + k0 + lcol),
                                             (las_void*)(&Blds[buf][c * 512]), 16, 0, 0);
        }
    };

    const int NT = K / 64;
    STAGE(0, 0);
    STAGE(1, 64);

    for (int ts = 0; ts < NT; ++ts) {
        if (ts < NT - 1) { WAIT_VM6(); }
        else             { WAIT_VM0(); }
        BAR();
        const u16* Ab = Alds[ts & 1];
        const u16* Bb = Blds[ts & 1];
        #pragma unroll
        for (int ks = 0; ks < 2; ++ks) {
            const int sl = ks * 4 + fg;
            bf16x8 af[4], bf[2];
            #pragma unroll
            for (int mi = 0; mi < 4; ++mi)
                af[mi] = *reinterpret_cast<const bf16x8*>(&Ab[frag_off(mi * 16 + frow, sl)]);
            #pragma unroll
            for (int nc = 0; nc < 2; ++nc)
                bf[nc] = *reinterpret_cast<const bf16x8*>(&Bb[frag_off(wv * 32 + nc * 16 + frow, sl)]);
            #pragma unroll
            for (int mi = 0; mi < 4; ++mi)
                #pragma unroll
                for (int nc = 0; nc < 2; ++nc)
                    acc[mi][nc] = __builtin_amdgcn_mfma_f32_16x16x32_bf16(af[mi], bf[nc], acc[mi][nc], 0, 0, 0);
        }
        BAR();
        if (ts < NT - 2) STAGE(ts & 1, (ts + 2) * 64);
    }

    const int rbase = (lane >> 4) * 4;
    #pragma unroll
    for (int nc = 0; nc < 2; ++nc) {
        const int col = bn + wv * 32 + nc * 16 + frow;
        const float bv = bias[col];
        #pragma unroll
        for (int mi = 0; mi < 4; ++mi) {
            #pragma unroll
            for (int j = 0; j < 4; ++j) {
                const int row = bm + mi * 16 + rbase + j;
                C[(size_t)row * N + col] = acc[mi][nc][j] + bv;
            }
        }
    }
}

// ---------------------------------------------------------------------------
// Attention (r22-validated: S-buffer softmax, 8 heads/block, rolling Regs
// prefetch, wave-local intra-head fences).
// ---------------------------------------------------------------------------
#define NCH 5  // ceil(49*24 / 256)
struct Regs { uint4 v[NCH]; };

static __device__ __forceinline__ void load_regs(Regs& r, const u16* __restrict__ base, int t)
{
    #pragma unroll
    for (int k = 0; k < NCH; ++k) {
        const int idx = t + k * 256;
        if (idx < TOK * 24) {
            const int n = idx / 24, c = idx - n * 24;
            r.v[k] = *reinterpret_cast<const uint4*>(base + (size_t)n * HQKV + c * 8);
        }
    }
}

static __device__ __forceinline__ void write_lds(const Regs& r, u16* __restrict__ QK,
                                                 u16* __restrict__ V, int t)
{
    #pragma unroll
    for (int k = 0; k < NCH; ++k) {
        const int idx = t + k * 256;
        if (idx < TOK * 24) {
            const int n = idx / 24, c24 = idx - n * 24;
            if (c24 < 8) {
                *reinterpret_cast<uint4*>(&QK[(n << 6) + ((c24 ^ (n & 7)) << 3)]) = r.v[k];
            } else {
                const int d0 = (c24 - 8) * 8;
                u16 vals[8];
                *reinterpret_cast<uint4*>(vals) = r.v[k];
                #pragma unroll
                for (int e = 0; e < 8; ++e)
                    V[swzV(d0 + e, n)] = vals[e];
            }
        }
    }
}

static __device__ __forceinline__ void attn_head(
    const u16* __restrict__ QK, const u16* __restrict__ V,
    float* __restrict__ S, u16* __restrict__ Ps,
    const float* __restrict__ bh_bias, u16* __restrict__ ab,
    int b, int h, int t)
{
    const int lane = t & 63;
    const int w    = t >> 6;
    const int fr   = lane & 15;
    const int fg   = lane >> 4;

    // QK^T
    bf16x8 qf = *reinterpret_cast<const bf16x8*>(&QK[swz(16 * w + fr, fg * 8)]);
    f32x4 sacc[4];
    #pragma unroll
    for (int nj = 0; nj < 4; ++nj) {
        bf16x8 kf = *reinterpret_cast<const bf16x8*>(&QK[swz(16 * nj + fr, 32 + fg * 8)]);
        sacc[nj] = __builtin_amdgcn_mfma_f32_16x16x32_bf16(qf, kf, (f32x4)0.0f, 0, 0, 0);
    }

    const float scale = 0.17677669529663687f;  // 32^-0.5
    #pragma unroll
    for (int nj = 0; nj < 4; ++nj) {
        #pragma unroll
        for (int j = 0; j < 4; ++j) {
            const int row = 16 * w + fg * 4 + j;
            const int col = 16 * nj + fr;
            const int rn = row < TOK ? row : TOK - 1;
            const int cm = col < TOK ? col : TOK - 1;
            S[row * 80 + col] = sacc[nj][j] * scale + bh_bias[rn * TOK + cm];
        }
    }
    LGKM0_FENCE();   // wave-local: S rows [16w,16w+16) read below by same wave

    // softmax: 4 threads per row (thread t -> row t>>2, all within wave w)
    {
        const int n = t >> 2, j = t & 3;
        const float* Sr = &S[n * 80];
        float v[16];
        #pragma unroll
        for (int e = 0; e < 8; ++e) v[e]     = Sr[8 * j + e];
        #pragma unroll
        for (int e = 0; e < 8; ++e) v[8 + e] = Sr[32 + 8 * j + e];

        float mx = -1e30f;
        #pragma unroll
        for (int e = 0; e < 8; ++e) mx = fmaxf(mx, v[e]);
        #pragma unroll
        for (int e = 0; e < 8; ++e)
            if (32 + 8 * j + e < TOK) mx = fmaxf(mx, v[8 + e]);
        mx = fmaxf(mx, __shfl_xor(mx, 1, 4));
        mx = fmaxf(mx, __shfl_xor(mx, 2, 4));

        float sum = 0.f;
        #pragma unroll
        for (int e = 0; e < 8; ++e) { v[e] = __expf(v[e] - mx); sum += v[e]; }
        #pragma unroll
        for (int e = 0; e < 8; ++e) {
            const float ev = (32 + 8 * j + e < TOK) ? __expf(v[8 + e] - mx) : 0.f;
            v[8 + e] = ev; sum += ev;
        }
        sum += __shfl_xor(sum, 1, 4);
        sum += __shfl_xor(sum, 2, 4);
        const float inv = 1.f / sum;

        uint4 o;
        o.x = f2bf(v[0] * inv)  | ((unsigned)f2bf(v[1] * inv)  << 16);
        o.y = f2bf(v[2] * inv)  | ((unsigned)f2bf(v[3] * inv)  << 16);
        o.z = f2bf(v[4] * inv)  | ((unsigned)f2bf(v[5] * inv)  << 16);
        o.w = f2bf(v[6] * inv)  | ((unsigned)f2bf(v[7] * inv)  << 16);
        *reinterpret_cast<uint4*>(&Ps[swz(n, 8 * j)]) = o;
        o.x = f2bf(v[8] * inv)  | ((unsigned)f2bf(v[9] * inv)  << 16);
        o.y = f2bf(v[10] * inv) | ((unsigned)f2bf(v[11] * inv) << 16);
        o.z = f2bf(v[12] * inv) | ((unsigned)f2bf(v[13] * inv) << 16);
        o.w = f2bf(v[14] * inv) | ((unsigned)f2bf(v[15] * inv) << 16);
        *reinterpret_cast<uint4*>(&Ps[swz(n, 32 + 8 * j)]) = o;
    }
    LGKM0_FENCE();   // wave-local: Ps rows [16w,16w+16) read below by same wave

    // PV
    f32x4 oacc[8];
    #pragma unroll
    for (int nj = 0; nj < 8; ++nj) oacc[nj] = (f32x4)0.0f;
    #pragma unroll
    for (int ks = 0; ks < 2; ++ks) {
        bf16x8 pf = *reinterpret_cast<const bf16x8*>(&Ps[swz(16 * w + fr, ks * 32 + fg * 8)]);
        #pragma unroll
        for (int nj = 0; nj < 8; ++nj) {
            bf16x8 vf = *reinterpret_cast<const bf16x8*>(&V[swzV(16 * nj + fr, ks * 32 + fg * 8)]);
            oacc[nj] = __builtin_amdgcn_mfma_f32_16x16x32_bf16(pf, vf, oacc[nj], 0, 0, 0);
        }
    }

    // ab store, pre-swizzled (T2) for proj-A (validated r10-r13)
    #pragma unroll
    for (int nj = 0; nj < 8; ++nj) {
        const int d = 16 * nj + fr;
        const int c = h * DHEAD + d;
        const int tp = c >> 6, sl = (c >> 3) & 7, cc = c & 7;
        #pragma unroll
        for (int j = 0; j < 4; ++j) {
            const int n = 16 * w + fg * 4 + j;
            if (n < TOK) {
                const int gr = b * TOK + n;
                ab[(size_t)gr * DHTOT + (tp << 6) + (((sl ^ (gr & 7)) << 3) | cc)] = f2bf(oacc[nj][j]);
            }
        }
    }
}

__global__ __launch_bounds__(256)
void attn_mfma(const u16* __restrict__ qkvb,          // [Mc][1536] bf16
               const float* __restrict__ bias_full,   // [NH][49*49]
               u16* __restrict__ ab)                  // [Mc][1024] pre-swz
{
    __shared__ __align__(16) u16  QKs[64 * 64];
    __shared__ __align__(16) u16  Vts[128 * 64];
    __shared__ __align__(16) float S[64 * 80];
    __shared__ __align__(16) u16  Ps[64 * 64];

    const int t = threadIdx.x;
    const int b = blockIdx.x;
    const u16* base = qkvb + (size_t)b * TOK * HQKV;

    // zero V pad (cols 48..63 = orig slots 6,7 of every row); never rewritten
    if (t < 128 * 2) {
        const int row = t >> 1, sl = 6 + (t & 1);
        *reinterpret_cast<uint4*>(&Vts[(row << 6) +
            (((sl ^ (row & 7) ^ ((row >> 3) & 7)) & 7) << 3)]) = make_uint4(0, 0, 0, 0);
    }
    __syncthreads();

    // gather head 0 directly (r13-validated loop)
    for (int flat = t; flat < TOK * 24; flat += 256) {
        const int n = flat / 24, c24 = flat - n * 24;
        uint4 u = *reinterpret_cast<const uint4*>(base + (size_t)n * HQKV + c24 * 8);
        if (c24 < 8) {
            *reinterpret_cast<uint4*>(&QKs[(n << 6) + ((c24 ^ (n & 7)) << 3)]) = u;
        } else {
            const int d0 = (c24 - 8) * 8;
            u16 vals[8];
            *reinterpret_cast<uint4*>(vals) = u;
            #pragma unroll
            for (int e = 0; e < 8; ++e)
                Vts[swzV(d0 + e, n)] = vals[e];
        }
    }

    Regs r;
    #pragma unroll 1
    for (int i = 0; i < NH; ++i) {
        if (i > 0) write_lds(r, QKs, Vts, t);            // head i into LDS
        if (i < NH - 1) load_regs(r, base + (i + 1) * 192, t);  // prefetch next
        LGKM0_BAR();                                     // LDS ready; loads in flight
        attn_head(QKs, Vts, S, Ps, bias_full + i * (TOK * TOK), ab, b, i, t);
        LGKM0_BAR();                                     // all reads of QKs/Vts done
    }
}

// ---------------------------------------------------------------------------
extern "C" void kernel_launch(void* const* d_in, const int* in_sizes, int n_in,
                              void* d_out, int out_size, void* d_ws, size_t ws_size,
                              hipStream_t stream)
{
    const float* x         = (const float*)d_in[0];
    const float* qkv_w     = (const float*)d_in[1];
    const float* qkv_b     = (const float*)d_in[2];
    const float* proj_w    = (const float*)d_in[3];
    const float* proj_b    = (const float*)d_in[4];
    const float* attn_bias = (const float*)d_in[5];
    const int*   bias_idxs = (const int*)d_in[6];

    const int Mtot  = in_sizes[0] / DIMM;            // 100352
    const int Btot  = Mtot / TOK;                    // 2048
    const int n_off = in_sizes[5] / NH;              // 49

    const size_t nWq = (size_t)HQKV * DIMM;
    const size_t nWp = (size_t)DIMM * DHTOT;
    float* bias_full = (float*)d_ws;                           // 76832 B
    u16*   wq        = (u16*)((char*)d_ws + 76832);
    u16*   wp        = wq + nWq;
    u16*   dyn       = wp + nWp;
    const size_t fixed_bytes = 76832 + (nWq + nWp) * sizeof(u16);
    // per-batch: qkvb 49*1536*2 + ab 49*1024*2
    const size_t per_batch = (size_t)TOK * (HQKV + DHTOT) * 2;

    if (ws_size <= fixed_bytes) return;
    long BcL = (long)((ws_size - fixed_bytes) / per_batch);
    int Bc = (int)((BcL / 128) * 128);       // keep Mc multiple of 128
    if (Bc <= 0) return;
    if (Bc > Btot) Bc = Btot;                // single chunk in practice (ws >= 1 GB)

    cast_swz<<<dim3(288), 256, 0, stream>>>(qkv_w, wq, DIMM / 8, (long)HQKV * (DIMM / 8));
    cast_swz<<<dim3(192), 256, 0, stream>>>(proj_w, wp, DHTOT / 8, (long)DIMM * (DHTOT / 8));
    bias_expand<<<dim3((NH * TOK * TOK + 255) / 256), 256, 0, stream>>>(attn_bias, bias_idxs, bias_full, n_off);

    for (int b0 = 0; b0 < Btot; b0 += Bc) {
        const int bc = (b0 + Bc <= Btot) ? Bc : (Btot - b0);   // multiple of 128
        const int Mc = bc * TOK;

        u16* qkvb = dyn;
        u16* abb  = qkvb + (size_t)Bc * TOK * HQKV;

        const float* xc   = x + (size_t)b0 * TOK * DIMM;
        float*       outc = (float*)d_out + (size_t)b0 * TOK * DIMM;

        gemm_qkv<<<dim3(((Mc + MCH - 1) / MCH) * 24), 256, 0, stream>>>(xc, wq, qkv_b, qkvb, Mc);

        attn_mfma<<<dim3(bc), 256, 0, stream>>>(qkvb, bias_full, abb);

        gemm_bf16_nt<<<dim3((Mc / 64) * (DIMM / 128)), 256, 0, stream>>>(abb, wp, proj_b, outc, Mc, DIMM, DHTOT);
    }
}

// Round 24
// 602.080 us; speedup vs baseline: 1.4143x; 1.4143x over previous
//
#include <hip/hip_runtime.h>
#include <cstddef>
#include <cstdint>

#define TOK    49      // tokens (7x7)
#define KD     32      // key dim
#define NH     8       // heads
#define DHEAD  128     // v head dim
#define HQKV   1536    // qkv channels
#define DHTOT  1024    // NH*DHEAD
#define DIMM   384     // model dim

typedef unsigned short u16;
typedef float  f32x4  __attribute__((ext_vector_type(4)));
typedef __bf16 bf16x8 __attribute__((ext_vector_type(8)));

typedef const __attribute__((address_space(1))) void gas_void;
typedef __attribute__((address_space(3))) void las_void;

static __device__ __forceinline__ u16 f2bf(float f) {
    unsigned int u = __builtin_bit_cast(unsigned int, f);
    return (u16)((u + 0x7fffu + ((u >> 16) & 1u)) >> 16);   // RNE
}

// XOR-swizzled index into a row-major [*][64] bf16 LDS image (QKs/Ps).
static __device__ __forceinline__ int swz(int row, int c) {
    return (row << 6) + ((((c >> 3) ^ (row & 7)) << 3) | (c & 7));
}

// Vts swizzle (validated r13): XOR both row&7 and (row>>3)&7.
static __device__ __forceinline__ int swzV(int row, int c) {
    return (row << 6) + ((((c >> 3) ^ (row & 7) ^ ((row >> 3) & 7)) << 3) | (c & 7));
}

// Bijective XCD-chunked remap (m204).
static __device__ __forceinline__ int xcd_chunk(int bid, int nwg) {
    const int xcd = bid & 7, slot = bid >> 3;
    const int q = nwg >> 3, r = nwg & 7;
    return (xcd < r ? xcd * (q + 1) : r * (q + 1) + (xcd - r) * q) + slot;
}

#define BAR() __builtin_amdgcn_s_barrier()
#define WAIT_VM6()  asm volatile("s_waitcnt vmcnt(6)"  ::: "memory")
#define WAIT_VM12() asm volatile("s_waitcnt vmcnt(12)" ::: "memory")
#define WAIT_VM0()  asm volatile("s_waitcnt vmcnt(0)"  ::: "memory")
// Barrier that does NOT drain vmcnt (r14/r17-validated).
#define LGKM0_BAR() do { asm volatile("s_waitcnt lgkmcnt(0)" ::: "memory"); \
                         __builtin_amdgcn_s_barrier(); } while (0)
// Wave-local LDS fence (rule #18): S/Ps producer and consumer are the SAME
// wave in attn_head, so no block barrier needed — just order LDS ops.
#define LGKM0_FENCE() do { asm volatile("s_waitcnt lgkmcnt(0)" ::: "memory"); \
                           __builtin_amdgcn_sched_barrier(0); } while (0)

// ---------------------------------------------------------------------------
// fp32 -> bf16 cast with T2 pre-swizzle (weights only; validated r10-r13).
// ---------------------------------------------------------------------------
__global__ __launch_bounds__(256)
void cast_swz(const float* __restrict__ in, u16* __restrict__ out, int K8, long nchunk)
{
    long i = (long)blockIdx.x * 256 + threadIdx.x;
    const long stride = (long)gridDim.x * 256;
    for (; i < nchunk; i += stride) {
        const long row = i / K8;
        const int  c8  = (int)(i - row * K8);
        const int  slot = c8 & 7, tpan = c8 >> 3;
        float4 v0 = reinterpret_cast<const float4*>(in)[i * 2];
        float4 v1 = reinterpret_cast<const float4*>(in)[i * 2 + 1];
        uint4 o;
        o.x = f2bf(v0.x) | ((unsigned)f2bf(v0.y) << 16);
        o.y = f2bf(v0.z) | ((unsigned)f2bf(v0.w) << 16);
        o.z = f2bf(v1.x) | ((unsigned)f2bf(v1.y) << 16);
        o.w = f2bf(v1.z) | ((unsigned)f2bf(v1.w) << 16);
        *reinterpret_cast<uint4*>(out + row * (long)K8 * 8 + tpan * 64 +
                                  ((slot ^ ((int)row & 7)) << 3)) = o;
    }
}

// ---------------------------------------------------------------------------
// bias_full[h][n*49+m] = attn_bias[h][bias_idxs[n*49+m]]
// ---------------------------------------------------------------------------
__global__ __launch_bounds__(256)
void bias_expand(const float* __restrict__ attn_bias, const int* __restrict__ idxs,
                 float* __restrict__ bias_full, int n_off)
{
    int i = blockIdx.x * 256 + threadIdx.x;
    if (i < NH * TOK * TOK) {
        int h = i / (TOK * TOK), s = i - h * (TOK * TOK);
        bias_full[i] = attn_bias[h * n_off + idxs[s]];
    }
}

static __device__ __forceinline__ int frag_off(int row, int ks8fg) {
    return (row << 6) + (((ks8fg ^ (row & 7)) << 3));
}

// ---------------------------------------------------------------------------
// QKV GEMM (validated r20/r22): BM=64 x dual-BN(256), fp32 A direct
// (reg-staged), B via global_load_lds, T4 counted waits. LDS 80 KB.
// ---------------------------------------------------------------------------
__global__ __launch_bounds__(256)
void gemm_qkv(const float* __restrict__ X,    // [M][384] fp32 (original x)
              const u16* __restrict__ W,      // [1536][384] bf16 pre-swz
              const float* __restrict__ bias, // [1536]
              u16* __restrict__ qkvb, int M)
{
    const int K = DIMM;                        // 6 K-steps
    const int NB2 = HQKV / 256;                // 6 dual-tiles
    const int nwg = (M / 64) * NB2;
    const int wgid = xcd_chunk(blockIdx.x, nwg);
    const int bm = (wgid / NB2) * 64;
    const int bn = (wgid % NB2) * 256;

    __shared__ u16 Alds[2][64 * 64];           // 16 KB
    __shared__ u16 B0lds[2][128 * 64];         // 32 KB
    __shared__ u16 B1lds[2][128 * 64];         // 32 KB

    const int t    = threadIdx.x;
    const int lane = t & 63;
    const int wv   = t >> 6;
    const int lrow = lane >> 3;
    const int lcol = (lane & 7) * 8;
    const int frow = lane & 15;
    const int fg   = lane >> 4;

    const int ar0 = t >> 3,           as0 = t & 7;
    const int ar1 = (t + 256) >> 3,   as1 = t & 7;

    f32x4 acc0[4][2], acc1[4][2];
    #pragma unroll
    for (int mi = 0; mi < 4; ++mi)
        #pragma unroll
        for (int nc = 0; nc < 2; ++nc) { acc0[mi][nc] = (f32x4)0.0f; acc1[mi][nc] = (f32x4)0.0f; }

    uint4 rA[2][4];

    auto ISSUE = [&](int buf, int k0) {
        #pragma unroll
        for (int i = 0; i < 4; ++i) {
            const int c   = i * 4 + wv;
            const int row = c * 8 + lrow;
            __builtin_amdgcn_global_load_lds((gas_void*)(W + (size_t)(bn + row) * K + k0 + lcol),
                                             (las_void*)(&B0lds[buf][c * 512]), 16, 0, 0);
        }
        #pragma unroll
        for (int i = 0; i < 4; ++i) {
            const int c   = i * 4 + wv;
            const int row = c * 8 + lrow;
            __builtin_amdgcn_global_load_lds((gas_void*)(W + (size_t)(bn + 128 + row) * K + k0 + lcol),
                                             (las_void*)(&B1lds[buf][c * 512]), 16, 0, 0);
        }
        const float* a0 = X + (size_t)(bm + ar0) * K + k0 + as0 * 8;
        const float* a1 = X + (size_t)(bm + ar1) * K + k0 + as1 * 8;
        rA[buf][0] = *reinterpret_cast<const uint4*>(a0);
        rA[buf][1] = *reinterpret_cast<const uint4*>(a0 + 4);
        rA[buf][2] = *reinterpret_cast<const uint4*>(a1);
        rA[buf][3] = *reinterpret_cast<const uint4*>(a1 + 4);
    };

    auto WRITE = [&](int buf) {
        #pragma unroll
        for (int l = 0; l < 2; ++l) {
            const int row = l ? ar1 : ar0;
            const int sl  = l ? as1 : as0;
            const float4 f0 = __builtin_bit_cast(float4, rA[buf][l * 2]);
            const float4 f1 = __builtin_bit_cast(float4, rA[buf][l * 2 + 1]);
            uint4 o;
            o.x = f2bf(f0.x) | ((unsigned)f2bf(f0.y) << 16);
            o.y = f2bf(f0.z) | ((unsigned)f2bf(f0.w) << 16);
            o.z = f2bf(f1.x) | ((unsigned)f2bf(f1.y) << 16);
            o.w = f2bf(f1.z) | ((unsigned)f2bf(f1.w) << 16);
            *reinterpret_cast<uint4*>(&Alds[buf][(row << 6) + ((sl ^ (row & 7)) << 3)]) = o;
        }
    };

    ISSUE(0, 0);
    ISSUE(1, 64);

    const int NT = 6;
    for (int ts = 0; ts < NT; ++ts) {
        WRITE(ts & 1);
        WAIT_VM12();
        LGKM0_BAR();
        const u16* Ab  = Alds[ts & 1];
        const u16* B0b = B0lds[ts & 1];
        const u16* B1b = B1lds[ts & 1];
        #pragma unroll
        for (int ks = 0; ks < 2; ++ks) {
            const int sl = ks * 4 + fg;
            bf16x8 af[4], b0[2], b1[2];
            #pragma unroll
            for (int mi = 0; mi < 4; ++mi)
                af[mi] = *reinterpret_cast<const bf16x8*>(&Ab[frag_off(mi * 16 + frow, sl)]);
            #pragma unroll
            for (int nc = 0; nc < 2; ++nc) {
                b0[nc] = *reinterpret_cast<const bf16x8*>(&B0b[frag_off(wv * 32 + nc * 16 + frow, sl)]);
                b1[nc] = *reinterpret_cast<const bf16x8*>(&B1b[frag_off(wv * 32 + nc * 16 + frow, sl)]);
            }
            #pragma unroll
            for (int mi = 0; mi < 4; ++mi)
                #pragma unroll
                for (int nc = 0; nc < 2; ++nc) {
                    acc0[mi][nc] = __builtin_amdgcn_mfma_f32_16x16x32_bf16(af[mi], b0[nc], acc0[mi][nc], 0, 0, 0);
                    acc1[mi][nc] = __builtin_amdgcn_mfma_f32_16x16x32_bf16(af[mi], b1[nc], acc1[mi][nc], 0, 0, 0);
                }
        }
        BAR();
        if (ts < NT - 2) ISSUE(ts & 1, (ts + 2) * 64);
    }

    const int rbase = (lane >> 4) * 4;
    #pragma unroll
    for (int half = 0; half < 2; ++half) {
        #pragma unroll
        for (int nc = 0; nc < 2; ++nc) {
            const int col = bn + half * 128 + wv * 32 + nc * 16 + frow;
            const float bv = bias[col];
            #pragma unroll
            for (int mi = 0; mi < 4; ++mi) {
                #pragma unroll
                for (int j = 0; j < 4; ++j) {
                    const int row = bm + mi * 16 + rbase + j;
                    const float v = half ? acc1[mi][nc][j] : acc0[mi][nc][j];
                    qkvb[(size_t)row * HQKV + col] = f2bf(v + bv);
                }
            }
        }
    }
}

// ---------------------------------------------------------------------------
// Proj GEMM (validated r18/r19): BM=64 x BN=128, T4 vmcnt(6).
// ---------------------------------------------------------------------------
__global__ __launch_bounds__(256)
void gemm_bf16_nt(const u16* __restrict__ A, const u16* __restrict__ W,
                  const float* __restrict__ bias, float* __restrict__ C,
                  int M, int N, int K)
{
    const int NB = N / 128;
    const int nwg = (M / 64) * NB;
    const int wgid = xcd_chunk(blockIdx.x, nwg);
    const int bm = (wgid / NB) * 64;
    const int bn = (wgid % NB) * 128;

    __shared__ u16 Alds[2][64 * 64];
    __shared__ u16 Blds[2][128 * 64];

    const int t    = threadIdx.x;
    const int lane = t & 63;
    const int wv   = t >> 6;
    const int lrow = lane >> 3;
    const int lcol = (lane & 7) * 8;
    const int frow = lane & 15;
    const int fg   = lane >> 4;

    f32x4 acc[4][2];
    #pragma unroll
    for (int mi = 0; mi < 4; ++mi)
        #pragma unroll
        for (int nc = 0; nc < 2; ++nc) acc[mi][nc] = (f32x4)0.0f;

    auto STAGE = [&](int buf, int k0) {
        #pragma unroll
        for (int i = 0; i < 2; ++i) {
            const int c   = i * 4 + wv;
            const int row = c * 8 + lrow;
            __builtin_amdgcn_global_load_lds((gas_void*)(A + (size_t)(bm + row) * K + k0 + lcol),
                                             (las_void*)(&Alds[buf][c * 512]), 16, 0, 0);
        }
        #pragma unroll
        for (int i = 0; i < 4; ++i) {
            const int c   = i * 4 + wv;
            const int row = c * 8 + lrow;
            __builtin_amdgcn_global_load_lds((gas_void*)(W + (size_t)(bn + row) * K + k0 + lcol),
                                             (las_void*)(&Blds[buf][c * 512]), 16, 0, 0);
        }
    };

    const int NT = K / 64;
    STAGE(0, 0);
    STAGE(1, 64);

    for (int ts = 0; ts < NT; ++ts) {
        if (ts < NT - 1) { WAIT_VM6(); }
        else             { WAIT_VM0(); }
        BAR();
        const u16* Ab = Alds[ts & 1];
        const u16* Bb = Blds[ts & 1];
        #pragma unroll
        for (int ks = 0; ks < 2; ++ks) {
            const int sl = ks * 4 + fg;
            bf16x8 af[4], bf[2];
            #pragma unroll
            for (int mi = 0; mi < 4; ++mi)
                af[mi] = *reinterpret_cast<const bf16x8*>(&Ab[frag_off(mi * 16 + frow, sl)]);
            #pragma unroll
            for (int nc = 0; nc < 2; ++nc)
                bf[nc] = *reinterpret_cast<const bf16x8*>(&Bb[frag_off(wv * 32 + nc * 16 + frow, sl)]);
            #pragma unroll
            for (int mi = 0; mi < 4; ++mi)
                #pragma unroll
                for (int nc = 0; nc < 2; ++nc)
                    acc[mi][nc] = __builtin_amdgcn_mfma_f32_16x16x32_bf16(af[mi], bf[nc], acc[mi][nc], 0, 0, 0);
        }
        BAR();
        if (ts < NT - 2) STAGE(ts & 1, (ts + 2) * 64);
    }

    const int rbase = (lane >> 4) * 4;
    #pragma unroll
    for (int nc = 0; nc < 2; ++nc) {
        const int col = bn + wv * 32 + nc * 16 + frow;
        const float bv = bias[col];
        #pragma unroll
        for (int mi = 0; mi < 4; ++mi) {
            #pragma unroll
            for (int j = 0; j < 4; ++j) {
                const int row = bm + mi * 16 + rbase + j;
                C[(size_t)row * N + col] = acc[mi][nc][j] + bv;
            }
        }
    }
}

// ---------------------------------------------------------------------------
// Attention (r22-validated: S-buffer softmax, 8 heads/block, rolling Regs
// prefetch, wave-local intra-head fences).
// ---------------------------------------------------------------------------
#define NCH 5  // ceil(49*24 / 256)
struct Regs { uint4 v[NCH]; };

static __device__ __forceinline__ void load_regs(Regs& r, const u16* __restrict__ base, int t)
{
    #pragma unroll
    for (int k = 0; k < NCH; ++k) {
        const int idx = t + k * 256;
        if (idx < TOK * 24) {
            const int n = idx / 24, c = idx - n * 24;
            r.v[k] = *reinterpret_cast<const uint4*>(base + (size_t)n * HQKV + c * 8);
        }
    }
}

static __device__ __forceinline__ void write_lds(const Regs& r, u16* __restrict__ QK,
                                                 u16* __restrict__ V, int t)
{
    #pragma unroll
    for (int k = 0; k < NCH; ++k) {
        const int idx = t + k * 256;
        if (idx < TOK * 24) {
            const int n = idx / 24, c24 = idx - n * 24;
            if (c24 < 8) {
                *reinterpret_cast<uint4*>(&QK[(n << 6) + ((c24 ^ (n & 7)) << 3)]) = r.v[k];
            } else {
                const int d0 = (c24 - 8) * 8;
                u16 vals[8];
                *reinterpret_cast<uint4*>(vals) = r.v[k];
                #pragma unroll
                for (int e = 0; e < 8; ++e)
                    V[swzV(d0 + e, n)] = vals[e];
            }
        }
    }
}

static __device__ __forceinline__ void attn_head(
    const u16* __restrict__ QK, const u16* __restrict__ V,
    float* __restrict__ S, u16* __restrict__ Ps,
    const float* __restrict__ bh_bias, u16* __restrict__ ab,
    int b, int h, int t)
{
    const int lane = t & 63;
    const int w    = t >> 6;
    const int fr   = lane & 15;
    const int fg   = lane >> 4;

    // QK^T
    bf16x8 qf = *reinterpret_cast<const bf16x8*>(&QK[swz(16 * w + fr, fg * 8)]);
    f32x4 sacc[4];
    #pragma unroll
    for (int nj = 0; nj < 4; ++nj) {
        bf16x8 kf = *reinterpret_cast<const bf16x8*>(&QK[swz(16 * nj + fr, 32 + fg * 8)]);
        sacc[nj] = __builtin_amdgcn_mfma_f32_16x16x32_bf16(qf, kf, (f32x4)0.0f, 0, 0, 0);
    }

    const float scale = 0.17677669529663687f;  // 32^-0.5
    #pragma unroll
    for (int nj = 0; nj < 4; ++nj) {
        #pragma unroll
        for (int j = 0; j < 4; ++j) {
            const int row = 16 * w + fg * 4 + j;
            const int col = 16 * nj + fr;
            const int rn = row < TOK ? row : TOK - 1;
            const int cm = col < TOK ? col : TOK - 1;
            S[row * 80 + col] = sacc[nj][j] * scale + bh_bias[rn * TOK + cm];
        }
    }
    LGKM0_FENCE();   // wave-local: S rows [16w,16w+16) read below by same wave

    // softmax: 4 threads per row (thread t -> row t>>2, all within wave w)
    {
        const int n = t >> 2, j = t & 3;
        const float* Sr = &S[n * 80];
        float v[16];
        #pragma unroll
        for (int e = 0; e < 8; ++e) v[e]     = Sr[8 * j + e];
        #pragma unroll
        for (int e = 0; e < 8; ++e) v[8 + e] = Sr[32 + 8 * j + e];

        float mx = -1e30f;
        #pragma unroll
        for (int e = 0; e < 8; ++e) mx = fmaxf(mx, v[e]);
        #pragma unroll
        for (int e = 0; e < 8; ++e)
            if (32 + 8 * j + e < TOK) mx = fmaxf(mx, v[8 + e]);
        mx = fmaxf(mx, __shfl_xor(mx, 1, 4));
        mx = fmaxf(mx, __shfl_xor(mx, 2, 4));

        float sum = 0.f;
        #pragma unroll
        for (int e = 0; e < 8; ++e) { v[e] = __expf(v[e] - mx); sum += v[e]; }
        #pragma unroll
        for (int e = 0; e < 8; ++e) {
            const float ev = (32 + 8 * j + e < TOK) ? __expf(v[8 + e] - mx) : 0.f;
            v[8 + e] = ev; sum += ev;
        }
        sum += __shfl_xor(sum, 1, 4);
        sum += __shfl_xor(sum, 2, 4);
        const float inv = 1.f / sum;

        uint4 o;
        o.x = f2bf(v[0] * inv)  | ((unsigned)f2bf(v[1] * inv)  << 16);
        o.y = f2bf(v[2] * inv)  | ((unsigned)f2bf(v[3] * inv)  << 16);
        o.z = f2bf(v[4] * inv)  | ((unsigned)f2bf(v[5] * inv)  << 16);
        o.w = f2bf(v[6] * inv)  | ((unsigned)f2bf(v[7] * inv)  << 16);
        *reinterpret_cast<uint4*>(&Ps[swz(n, 8 * j)]) = o;
        o.x = f2bf(v[8] * inv)  | ((unsigned)f2bf(v[9] * inv)  << 16);
        o.y = f2bf(v[10] * inv) | ((unsigned)f2bf(v[11] * inv) << 16);
        o.z = f2bf(v[12] * inv) | ((unsigned)f2bf(v[13] * inv) << 16);
        o.w = f2bf(v[14] * inv) | ((unsigned)f2bf(v[15] * inv) << 16);
        *reinterpret_cast<uint4*>(&Ps[swz(n, 32 + 8 * j)]) = o;
    }
    LGKM0_FENCE();   // wave-local: Ps rows [16w,16w+16) read below by same wave

    // PV
    f32x4 oacc[8];
    #pragma unroll
    for (int nj = 0; nj < 8; ++nj) oacc[nj] = (f32x4)0.0f;
    #pragma unroll
    for (int ks = 0; ks < 2; ++ks) {
        bf16x8 pf = *reinterpret_cast<const bf16x8*>(&Ps[swz(16 * w + fr, ks * 32 + fg * 8)]);
        #pragma unroll
        for (int nj = 0; nj < 8; ++nj) {
            bf16x8 vf = *reinterpret_cast<const bf16x8*>(&V[swzV(16 * nj + fr, ks * 32 + fg * 8)]);
            oacc[nj] = __builtin_amdgcn_mfma_f32_16x16x32_bf16(pf, vf, oacc[nj], 0, 0, 0);
        }
    }

    // ab store, pre-swizzled (T2) for proj-A (validated r10-r13)
    #pragma unroll
    for (int nj = 0; nj < 8; ++nj) {
        const int d = 16 * nj + fr;
        const int c = h * DHEAD + d;
        const int tp = c >> 6, sl = (c >> 3) & 7, cc = c & 7;
        #pragma unroll
        for (int j = 0; j < 4; ++j) {
            const int n = 16 * w + fg * 4 + j;
            if (n < TOK) {
                const int gr = b * TOK + n;
                ab[(size_t)gr * DHTOT + (tp << 6) + (((sl ^ (gr & 7)) << 3) | cc)] = f2bf(oacc[nj][j]);
            }
        }
    }
}

__global__ __launch_bounds__(256)
void attn_mfma(const u16* __restrict__ qkvb,          // [Mc][1536] bf16
               const float* __restrict__ bias_full,   // [NH][49*49]
               u16* __restrict__ ab)                  // [Mc][1024] pre-swz
{
    __shared__ __align__(16) u16  QKs[64 * 64];
    __shared__ __align__(16) u16  Vts[128 * 64];
    __shared__ __align__(16) float S[64 * 80];
    __shared__ __align__(16) u16  Ps[64 * 64];

    const int t = threadIdx.x;
    const int b = blockIdx.x;
    const u16* base = qkvb + (size_t)b * TOK * HQKV;

    // zero V pad (cols 48..63 = orig slots 6,7 of every row); never rewritten
    if (t < 128 * 2) {
        const int row = t >> 1, sl = 6 + (t & 1);
        *reinterpret_cast<uint4*>(&Vts[(row << 6) +
            (((sl ^ (row & 7) ^ ((row >> 3) & 7)) & 7) << 3)]) = make_uint4(0, 0, 0, 0);
    }
    __syncthreads();

    // gather head 0 directly (r13-validated loop)
    for (int flat = t; flat < TOK * 24; flat += 256) {
        const int n = flat / 24, c24 = flat - n * 24;
        uint4 u = *reinterpret_cast<const uint4*>(base + (size_t)n * HQKV + c24 * 8);
        if (c24 < 8) {
            *reinterpret_cast<uint4*>(&QKs[(n << 6) + ((c24 ^ (n & 7)) << 3)]) = u;
        } else {
            const int d0 = (c24 - 8) * 8;
            u16 vals[8];
            *reinterpret_cast<uint4*>(vals) = u;
            #pragma unroll
            for (int e = 0; e < 8; ++e)
                Vts[swzV(d0 + e, n)] = vals[e];
        }
    }

    Regs r;
    #pragma unroll 1
    for (int i = 0; i < NH; ++i) {
        if (i > 0) write_lds(r, QKs, Vts, t);            // head i into LDS
        if (i < NH - 1) load_regs(r, base + (i + 1) * 192, t);  // prefetch next
        LGKM0_BAR();                                     // LDS ready; loads in flight
        attn_head(QKs, Vts, S, Ps, bias_full + i * (TOK * TOK), ab, b, i, t);
        LGKM0_BAR();                                     // all reads of QKs/Vts done
    }
}

// ---------------------------------------------------------------------------
extern "C" void kernel_launch(void* const* d_in, const int* in_sizes, int n_in,
                              void* d_out, int out_size, void* d_ws, size_t ws_size,
                              hipStream_t stream)
{
    const float* x         = (const float*)d_in[0];
    const float* qkv_w     = (const float*)d_in[1];
    const float* qkv_b     = (const float*)d_in[2];
    const float* proj_w    = (const float*)d_in[3];
    const float* proj_b    = (const float*)d_in[4];
    const float* attn_bias = (const float*)d_in[5];
    const int*   bias_idxs = (const int*)d_in[6];

    const int Mtot  = in_sizes[0] / DIMM;            // 100352
    const int Btot  = Mtot / TOK;                    // 2048
    const int n_off = in_sizes[5] / NH;              // 49

    const size_t nWq = (size_t)HQKV * DIMM;
    const size_t nWp = (size_t)DIMM * DHTOT;
    float* bias_full = (float*)d_ws;                           // 76832 B
    u16*   wq        = (u16*)((char*)d_ws + 76832);
    u16*   wp        = wq + nWq;
    u16*   dyn       = wp + nWp;
    const size_t fixed_bytes = 76832 + (nWq + nWp) * sizeof(u16);
    // per-batch: qkvb 49*1536*2 + ab 49*1024*2
    const size_t per_batch = (size_t)TOK * (HQKV + DHTOT) * 2;

    if (ws_size <= fixed_bytes) return;
    long BcL = (long)((ws_size - fixed_bytes) / per_batch);
    int Bc = (int)((BcL / 128) * 128);       // keep Mc multiple of 128
    if (Bc <= 0) return;
    if (Bc > Btot) Bc = Btot;                // single chunk in practice (ws >= 1 GB)

    cast_swz<<<dim3(288), 256, 0, stream>>>(qkv_w, wq, DIMM / 8, (long)HQKV * (DIMM / 8));
    cast_swz<<<dim3(192), 256, 0, stream>>>(proj_w, wp, DHTOT / 8, (long)DIMM * (DHTOT / 8));
    bias_expand<<<dim3((NH * TOK * TOK + 255) / 256), 256, 0, stream>>>(attn_bias, bias_idxs, bias_full, n_off);

    for (int b0 = 0; b0 < Btot; b0 += Bc) {
        const int bc = (b0 + Bc <= Btot) ? Bc : (Btot - b0);   // multiple of 128
        const int Mc = bc * TOK;

        u16* qkvb = dyn;
        u16* abb  = qkvb + (size_t)Bc * TOK * HQKV;

        const float* xc   = x + (size_t)b0 * TOK * DIMM;
        float*       outc = (float*)d_out + (size_t)b0 * TOK * DIMM;

        gemm_qkv<<<dim3((Mc / 64) * (HQKV / 256)), 256, 0, stream>>>(xc, wq, qkv_b, qkvb, Mc);

        attn_mfma<<<dim3(bc), 256, 0, stream>>>(qkvb, bias_full, abb);

        gemm_bf16_nt<<<dim3((Mc / 64) * (DIMM / 128)), 256, 0, stream>>>(abb, wp, proj_b, outc, Mc, DIMM, DHTOT);
    }
}